// Round 3
// baseline (619.169 us; speedup 1.0000x reference)
//
#include <hip/hip_runtime.h>
#include <stdint.h>

#define DEV __device__ __forceinline__
typedef unsigned short u16; typedef unsigned int u32; typedef unsigned long long u64;
typedef __attribute__((ext_vector_type(8))) short s8v;   // 8 x bf16 (4 VGPR)
typedef __attribute__((ext_vector_type(4))) float f4v;   // MFMA acc

#define Bb 512
#define Tt 256
#define Ff 64
#define Hh 128
#define Dd 192

DEV u16 f2bf(float f){ u32 u = __builtin_bit_cast(u32, f); u32 r = (u + 0x7fffu + ((u>>16)&1u)) >> 16; return (u16)r; }
DEV float bf2f(u16 h){ u32 u = ((u32)h)<<16; return __builtin_bit_cast(float, u); }
DEV float sigm(float x){ return __builtin_amdgcn_rcpf(1.0f + __expf(-x)); }
DEV float tanhfast(float x){ return 1.0f - 2.0f*__builtin_amdgcn_rcpf(1.0f + __expf(2.0f*x)); }

DEV f4v mfma16(s8v a, s8v b, f4v c){ return __builtin_amdgcn_mfma_f32_16x16x32_bf16(a, b, c, 0, 0, 0); }

// hx LDS element index for (k, col). Layout: [k/8 block][16 cols (xor-swizzled)][8 k]
DEV int hxe(int k, int c){ int blk = k>>3; return (blk*16 + (c ^ ((blk&3)<<1)))*8 + (k&7); }

DEV s8v pack8(const float* p){
  const float4 a = *(const float4*)p; const float4 b = *(const float4*)(p+4);
  s8v r; r[0]=(short)f2bf(a.x); r[1]=(short)f2bf(a.y); r[2]=(short)f2bf(a.z); r[3]=(short)f2bf(a.w);
  r[4]=(short)f2bf(b.x); r[5]=(short)f2bf(b.y); r[6]=(short)f2bf(b.z); r[7]=(short)f2bf(b.w); return r;
}
DEV u32 pk2(float a, float b){ return (u32)f2bf(a) | ((u32)f2bf(b)<<16); }

// ---------------- prelim: last_obs, x_last, score const term ----------------
__global__ __launch_bounds__(64) void prelim_k(const float* __restrict__ x,
    const float* __restrict__ Watt, const float* __restrict__ batt,
    float* __restrict__ xlast, float* __restrict__ c0, int* __restrict__ lastobs)
{
  int b = blockIdx.x, tid = threadIdx.x;
  int cnt = 0;
  for (int it = 0; it < 4; ++it){
    int t = it*64 + tid;
    const float4* p = (const float4*)(x + ((size_t)b*Tt + t)*Ff);
    float s = 0.0f;
    #pragma unroll
    for (int q = 0; q < 16; ++q){ float4 v = p[q]; s += fabsf(v.x)+fabsf(v.y)+fabsf(v.z)+fabsf(v.w); }
    u64 m = __ballot(s != 0.0f);
    cnt += __popcll(m);
  }
  int last = cnt - 1;
  int li = (last < 0) ? (Tt-1) : last;
  float xl = x[((size_t)b*Tt + li)*Ff + tid];
  xlast[b*Ff + tid] = xl;
  float p = xl * Watt[Hh + tid];
  for (int off = 32; off; off >>= 1) p += __shfl_down(p, off);
  if (tid == 0){ c0[b] = p + batt[0]; lastobs[b] = last; }
}

// ---------------- decoder weight prep: frag-major bf16 for both W_hh_cs and W_ih_cs --------
__global__ __launch_bounds__(256) void prep_wd_k(const float* __restrict__ Whhcs,
    const float* __restrict__ Wihcs, u16* __restrict__ Wd, u16* __restrict__ WdIH)
{
  int idx = blockIdx.x*256 + threadIdx.x;          // < 294912
  int j = idx & 7, lane = (idx>>3)&63;
  int f = idx>>9;                                  // < 576
  int kt = f % 6; int mtr = f/6;                   // mtr < 96
  int mt = mtr % 48, r = mtr/48;
  int ut = mt>>2, g = mt&3;
  int row = g*Dd + ut*16 + (lane&15);
  int k = kt*32 + (lane>>4)*8 + j;
  size_t src = ((size_t)r*768 + row)*Dd + k;
  Wd[idx]   = f2bf(Whhcs[src]);
  WdIH[idx] = f2bf(Wihcs[src]);
}

// ---------------- xw = ha @ W_ih_cs^T  (acc-init fragments, bf16) ----------------
__global__ __launch_bounds__(64) void xw_k(const u16* __restrict__ WdIH,
    const float* __restrict__ ha, u16* __restrict__ xwg)
{
  int lane = threadIdx.x, l15 = lane&15, l4 = lane>>4;
  int cg = blockIdx.x & 3, rm = blockIdx.x >> 2;   // rm < 96
  s8v af[6];
  #pragma unroll
  for (int kt=0;kt<6;++kt) af[kt] = *(const s8v*)(WdIH + (size_t)(rm*6+kt)*512 + lane*8);
  #pragma unroll
  for (int ct=0; ct<8; ++ct){
    int c = cg*128 + ct*16 + l15;
    f4v a = {0,0,0,0};
    #pragma unroll
    for (int kt=0;kt<6;++kt){
      s8v b = pack8(ha + (size_t)c*Dd + kt*32 + l4*8);
      a = mfma16(af[kt], b, a);
    }
    int bg = cg*8 + ct;
    int base = bg*24576 + rm*256 + l15*16 + l4*4;  // elements
    *(u32*)&xwg[base]   = pk2(a[0], a[1]);
    *(u32*)&xwg[base+2] = pk2(a[2], a[3]);
  }
}

// ---------------- encoder: LSTM + fused long_pred + fused online attention ----------------
__global__ __launch_bounds__(512,2) void enc_k(
    const float* __restrict__ x, const float* __restrict__ Whh, const float* __restrict__ Wih,
    const float* __restrict__ Wlong, const float* __restrict__ blong, const float* __restrict__ Watt,
    const float* __restrict__ xlast, const float* __restrict__ c0v, const int* __restrict__ lastobs,
    float* __restrict__ lp_out, float* __restrict__ ha)
{
  __shared__ __align__(16) u16 hx[2][3072];
  __shared__ float lp_lds[2][16*68];
  __shared__ float sarr[2][16];
  const int tid = threadIdx.x, wid = tid>>6, lane = tid&63, l15 = lane&15, l4 = lane>>4;
  const int b0 = blockIdx.x*16;
  const int xrow = tid>>5, xc2 = (tid&31)*2;

  // weight fragments
  s8v wf[4][6];
  #pragma unroll
  for (int mt = 0; mt < 4; ++mt){
    int gate = mt*Hh + wid*16 + l15;
    #pragma unroll
    for (int kt = 0; kt < 6; ++kt){
      int k0 = kt*32 + l4*8;
      if (kt < 4) wf[mt][kt] = pack8(Whh + (size_t)gate*Hh + k0);
      else        wf[mt][kt] = pack8(Wih + (size_t)gate*Ff + (k0 - Hh));
    }
  }
  s8v wfx[6];
  {
    s8v z = {0,0,0,0,0,0,0,0};
    #pragma unroll
    for (int kt = 0; kt < 6; ++kt) wfx[kt] = z;
    if (wid < 4){
      int f = wid*16 + l15;
      #pragma unroll
      for (int kt = 0; kt < 4; ++kt) wfx[kt] = pack8(Wlong + (size_t)f*Hh + kt*32 + l4*8);
    } else if (wid == 4 && l15 == 0){
      #pragma unroll
      for (int kt = 0; kt < 4; ++kt) wfx[kt] = pack8(Watt + kt*32 + l4*8);
    }
  }
  float bl[4] = {0,0,0,0};
  if (wid < 4){
    #pragma unroll
    for (int j = 0; j < 4; ++j) bl[j] = blong[wid*16 + l4*4 + j];
  }
  const int   lastb = lastobs[b0 + l15];
  const float c0b   = c0v[b0 + l15];

  // invariant LDS addresses
  const int he0 = hxe(wid*16 + l4*4, l15);           // h write (b64)
  const int xe0 = hxe(Hh + xc2, xrow);               // x write (b32)

  // init hx[0]: h=0 (k<128 -> first 512 u64), x_0
  ((u64*)hx[0])[tid] = 0ull;                         // FIX: all 512 threads (was tid<256)
  {
    float2 xv = *(const float2*)(x + ((size_t)(b0+xrow)*Tt + 0)*Ff + xc2);
    *(u32*)&hx[0][xe0] = pk2(xv.x, xv.y);
  }
  // x prefetch: xa holds x_{tb+1..tb+4}
  float2 xa[4], xb[4];
  #pragma unroll
  for (int u = 0; u < 4; ++u)
    xa[u] = *(const float2*)(x + ((size_t)(b0+xrow)*Tt + (1+u))*Ff + xc2);
  __syncthreads();

  float cst[4] = {0,0,0,0}, hp[4] = {0,0,0,0}, hpp[4] = {0,0,0,0};
  float accA[4] = {0,0,0,0}, mrun = -3.0e38f, zrun = 0.0f;

  for (int tb = 0; tb < Tt; tb += 4){
    // prefetch x_{tb+5..tb+8}
    #pragma unroll
    for (int u = 0; u < 4; ++u){
      int tp = tb + 5 + u; if (tp > Tt-1) tp = Tt-1;
      xb[u] = *(const float2*)(x + ((size_t)(b0+xrow)*Tt + tp)*Ff + xc2);
    }
    #pragma unroll
    for (int u = 0; u < 4; ++u){
      const int t = tb + u;
      const int curb = u & 1, nxtb = curb ^ 1;
      s8v bf[6];
      #pragma unroll
      for (int kt = 0; kt < 6; ++kt)
        bf[kt] = *(const s8v*)&hx[curb][((kt*4 + l4)*16 + (l15 ^ (l4<<1)))*8];

      f4v acc0 = {0,0,0,0}, acc1 = {0,0,0,0}, acc2 = {0,0,0,0}, acc3 = {0,0,0,0}, accx = {0,0,0,0};
      #pragma unroll
      for (int kt = 0; kt < 6; ++kt){
        acc0 = mfma16(wf[0][kt], bf[kt], acc0);
        acc1 = mfma16(wf[1][kt], bf[kt], acc1);
        acc2 = mfma16(wf[2][kt], bf[kt], acc2);
        acc3 = mfma16(wf[3][kt], bf[kt], acc3);
      }
      if (wid < 5){
        #pragma unroll
        for (int kt = 0; kt < 6; ++kt) accx = mfma16(wfx[kt], bf[kt], accx);
      }
      if (wid == 4 && l4 == 0) sarr[nxtb][l15] = accx[0] + c0b;   // s_{t-1}

      float hnew[4];
      #pragma unroll
      for (int j = 0; j < 4; ++j){
        float cn = sigm(acc1[j])*cst[j] + sigm(acc0[j])*tanhfast(acc2[j]);
        cst[j] = cn;
        hnew[j] = sigm(acc3[j])*tanhfast(cn);
      }
      // online attention: pair (s_{t-2}, h_{t-2})
      if (t >= 2){
        float sv = sarr[curb][l15];
        if (t-2 < lastb){
          float mn = fmaxf(mrun, sv);
          float sc = __expf(mrun - mn);
          float e  = __expf(sv - mn);
          zrun = zrun*sc + e;
          #pragma unroll
          for (int j = 0; j < 4; ++j) accA[j] = accA[j]*sc + e*hpp[j];
          mrun = mn;
        }
      }
      #pragma unroll
      for (int j = 0; j < 4; ++j){ hpp[j] = hp[j]; hp[j] = hnew[j]; }
      // packed h write
      {
        u64 w = (u64)pk2(hnew[0],hnew[1]) | ((u64)pk2(hnew[2],hnew[3])<<32);
        *(u64*)&hx[nxtb][he0] = w;
      }
      if (t < Tt-1) *(u32*)&hx[nxtb][xe0] = pk2(xa[u].x, xa[u].y);
      if (wid < 4){
        #pragma unroll
        for (int j = 0; j < 4; ++j)
          lp_lds[nxtb][l15*68 + wid*16 + l4*4 + j] = accx[j] + bl[j];   // lp_{t-1}
      }
      if (t >= 2){
        float2 v; v.x = lp_lds[curb][xrow*68 + xc2]; v.y = lp_lds[curb][xrow*68 + xc2 + 1];
        *(float2*)(lp_out + ((size_t)(b0+xrow)*Tt + (t-2))*Ff + xc2) = v;
      }
      __syncthreads();
    }
    #pragma unroll
    for (int u = 0; u < 4; ++u) xa[u] = xb[u];
  }
  // epilogue (after loop: hx[0]=h_255, sarr[0]=s_254, lp_lds[0]=lp_254)
  {
    if (254 < lastb){
      float sv = sarr[0][l15];
      float mn = fmaxf(mrun, sv);
      float sc = __expf(mrun - mn);
      float e  = __expf(sv - mn);
      zrun = zrun*sc + e;
      #pragma unroll
      for (int j = 0; j < 4; ++j) accA[j] = accA[j]*sc + e*hpp[j];
      mrun = mn;
    }
    { float2 v; v.x = lp_lds[0][xrow*68 + xc2]; v.y = lp_lds[0][xrow*68 + xc2 + 1];
      *(float2*)(lp_out + ((size_t)(b0+xrow)*Tt + 254)*Ff + xc2) = v; }
    // lp_255 from h_255
    s8v bfE[4];
    #pragma unroll
    for (int kt = 0; kt < 4; ++kt)
      bfE[kt] = *(const s8v*)&hx[0][((kt*4 + l4)*16 + (l15 ^ (l4<<1)))*8];
    if (wid < 4){
      f4v accx = {0,0,0,0};
      #pragma unroll
      for (int kt = 0; kt < 4; ++kt) accx = mfma16(wfx[kt], bfE[kt], accx);
      #pragma unroll
      for (int j = 0; j < 4; ++j) lp_lds[1][l15*68 + wid*16 + l4*4 + j] = accx[j] + bl[j];
    }
    float inv = (zrun > 0.0f) ? __builtin_amdgcn_rcpf(zrun) : 0.0f;
    #pragma unroll
    for (int j = 0; j < 4; ++j)
      ha[(size_t)(b0 + l15)*Dd + wid*16 + l4*4 + j] = accA[j]*inv;
    __syncthreads();
    { float2 v; v.x = lp_lds[1][xrow*68 + xc2]; v.y = lp_lds[1][xrow*68 + xc2 + 1];
      *(float2*)(lp_out + ((size_t)(b0+xrow)*Tt + 255)*Ff + xc2) = v; }
    for (int q = tid; q < 16*Ff; q += 512){
      int r2 = q >> 6, f = q & 63;
      ha[(size_t)(b0 + r2)*Dd + Hh + f] = xlast[(b0 + r2)*Ff + f];
    }
  }
}

// ---------------- decoder v2: risk0 in registers, risk1 LDS(kt0,1)+streamed(kt2..5) ----------------
__global__ __launch_bounds__(256,1) void dec_k(const float* __restrict__ ha,
    const u16* __restrict__ Wd, const u16* __restrict__ xwg,
    const float* __restrict__ Wcs, const float* __restrict__ bcs, float* __restrict__ outs)
{
  __shared__ __align__(16) u16 hx[2][3072];          // 12 KB
  __shared__ __align__(16) u16 w1[48*2*512];         // 96 KB: risk1 kt0,1 frag chunks
  __shared__ __align__(16) u16 xwl[2*48*256];        // 48 KB: acc-init frags
  __shared__ float red[2][4][16];
  const int tid = threadIdx.x, wid = tid>>6, lane = tid&63, l15 = lane&15, l4 = lane>>4;
  const int b0 = blockIdx.x*16;

  // ha -> hx[0]
  #pragma unroll
  for (int it = 0; it < 3; ++it){
    int k = it*64 + (tid>>4)*4, c = tid&15;
    float4 v = *(const float4*)(ha + (size_t)(b0+c)*Dd + k);
    int e = hxe(k, c);
    *(u32*)&hx[0][e]   = pk2(v.x, v.y);
    *(u32*)&hx[0][e+2] = pk2(v.z, v.w);
  }
  // xwl copy (49152 B)
  {
    const u16* src = xwg + (size_t)blockIdx.x*24576;
    #pragma unroll
    for (int i = 0; i < 12; ++i){
      int off = (i*256 + tid)*8;
      *(s8v*)&xwl[off] = *(const s8v*)(src + off);
    }
  }
  // w1 copy: dst chunk (mtg*2+kt)*512  <-  Wd[((48+mtg)*6+kt)*512]
  #pragma unroll
  for (int i = 0; i < 24; ++i){
    int off = (i*256 + tid)*8;
    int chunk = off>>9, inner = off&511;
    int mtg = chunk>>1, kt = chunk&1;
    *(s8v*)&w1[off] = *(const s8v*)(Wd + (size_t)((48+mtg)*6+kt)*512 + inner);
  }
  // risk0 weights in registers
  s8v wreg[12][6];
  #pragma unroll
  for (int m = 0; m < 12; ++m)
    #pragma unroll
    for (int kt = 0; kt < 6; ++kt)
      wreg[m][kt] = *(const s8v*)(Wd + (size_t)((wid*12+m)*6+kt)*512 + lane*8);

  float cst[3][4], wcsr0[3][4], wcsr1[3][4];
  #pragma unroll
  for (int ut = 0; ut < 3; ++ut){
    int u0 = (wid*3+ut)*16 + l4*4;
    #pragma unroll
    for (int jj = 0; jj < 4; ++jj){
      cst[ut][jj]   = ha[(size_t)(b0+l15)*Dd + u0 + jj];
      wcsr0[ut][jj] = Wcs[u0 + jj];
      wcsr1[ut][jj] = Wcs[Dd + u0 + jj];
    }
  }
  const float bc0 = bcs[0], bc1 = bcs[1];
  __syncthreads();

  const u16* wsb = Wd + (size_t)(48 + wid*12)*6*512 + lane*8;   // risk1 stream base
  s8v lA[4], lB[4];
#define LOADA(m) { _Pragma("unroll") for (int q=0;q<4;++q) lA[q] = *(const s8v*)(wsb + (size_t)((m)*6 + 2 + q)*512); }
#define LOADB(m) { _Pragma("unroll") for (int q=0;q<4;++q) lB[q] = *(const s8v*)(wsb + (size_t)((m)*6 + 2 + q)*512); }

#define XWINIT(r_, m_, a_) { \
    int xb_ = ((r_)*48 + wid*12 + (m_))*256 + l15*16 + l4*4; \
    u32 q0 = *(const u32*)&xwl[xb_]; u32 q1 = *(const u32*)&xwl[xb_+2]; \
    a_[0] = bf2f((u16)q0); a_[1] = bf2f((u16)(q0>>16)); \
    a_[2] = bf2f((u16)q1); a_[3] = bf2f((u16)(q1>>16)); }

#define CELLS(r_, ut_, wcs_, a0_, a1_, a2_, a3_) { \
    float hn0,hn1,hn2,hn3; \
    { float cn = sigm(a1_[0])*cst[ut_][0] + sigm(a0_[0])*tanhfast(a2_[0]); cst[ut_][0]=cn; hn0 = sigm(a3_[0])*tanhfast(cn); } \
    { float cn = sigm(a1_[1])*cst[ut_][1] + sigm(a0_[1])*tanhfast(a2_[1]); cst[ut_][1]=cn; hn1 = sigm(a3_[1])*tanhfast(cn); } \
    { float cn = sigm(a1_[2])*cst[ut_][2] + sigm(a0_[2])*tanhfast(a2_[2]); cst[ut_][2]=cn; hn2 = sigm(a3_[2])*tanhfast(cn); } \
    { float cn = sigm(a1_[3])*cst[ut_][3] + sigm(a0_[3])*tanhfast(a2_[3]); cst[ut_][3]=cn; hn3 = sigm(a3_[3])*tanhfast(cn); } \
    part += hn0*wcs_[ut_][0] + hn1*wcs_[ut_][1] + hn2*wcs_[ut_][2] + hn3*wcs_[ut_][3]; \
    int u0_ = (wid*3+(ut_))*16 + l4*4; \
    int e0_ = (((u0_>>3)*16) + (l15 ^ (((u0_>>3)&3)<<1)))*8 + (u0_&7); \
    u64 w_ = (u64)pk2(hn0,hn1) | ((u64)pk2(hn2,hn3)<<32); \
    *(u64*)&hx[nxtb_][e0_] = w_; }

  for (int sp = 0; sp < 32; ++sp){
    // ---------- EVEN step s=2sp, r=0: reads hx[0], writes hx[1] ----------
    {
      LOADA(0); LOADB(1);               // prefetch odd-step streams m=0,1
      const int nxtb_ = 1;
      s8v bf[6];
      #pragma unroll
      for (int kt = 0; kt < 6; ++kt)
        bf[kt] = *(const s8v*)&hx[0][((kt*4 + l4)*16 + (l15 ^ (l4<<1)))*8];
      float part = 0.0f;
      #pragma unroll
      for (int ut = 0; ut < 3; ++ut){
        f4v a0,a1,a2,a3;
        XWINIT(0, ut*4+0, a0); XWINIT(0, ut*4+1, a1); XWINIT(0, ut*4+2, a2); XWINIT(0, ut*4+3, a3);
        #pragma unroll
        for (int kt = 0; kt < 6; ++kt){
          a0 = mfma16(wreg[ut*4+0][kt], bf[kt], a0);
          a1 = mfma16(wreg[ut*4+1][kt], bf[kt], a1);
          a2 = mfma16(wreg[ut*4+2][kt], bf[kt], a2);
          a3 = mfma16(wreg[ut*4+3][kt], bf[kt], a3);
        }
        CELLS(0, ut, wcsr0, a0, a1, a2, a3);
      }
      part += __shfl_xor(part, 16); part += __shfl_xor(part, 32);
      if (l4 == 0) red[0][wid][l15] = part;
      __syncthreads();
      if (tid < 16)
        outs[(sp*2)*Bb + b0 + tid] = sigm(red[0][0][tid]+red[0][1][tid]+red[0][2][tid]+red[0][3][tid] + bc0);
    }
    // ---------- ODD step s=2sp+1, r=1: reads hx[1], writes hx[0] ----------
    {
      const int nxtb_ = 0;
      s8v bf[6];
      #pragma unroll
      for (int kt = 0; kt < 6; ++kt)
        bf[kt] = *(const s8v*)&hx[1][((kt*4 + l4)*16 + (l15 ^ (l4<<1)))*8];
      float part = 0.0f;
      #pragma unroll
      for (int ut = 0; ut < 3; ++ut){
        f4v a0,a1,a2,a3;
        XWINIT(1, ut*4+0, a0); XWINIT(1, ut*4+1, a1); XWINIT(1, ut*4+2, a2); XWINIT(1, ut*4+3, a3);
        #pragma unroll
        for (int g = 0; g < 4; ++g){
          const int m = ut*4 + g;
          f4v* ap = (g==0)? &a0 : (g==1)? &a1 : (g==2)? &a2 : &a3;
          f4v a = *ap;
          { s8v w0 = *(const s8v*)&w1[((wid*12+m)*2+0)*512 + lane*8];
            s8v w1v= *(const s8v*)&w1[((wid*12+m)*2+1)*512 + lane*8];
            a = mfma16(w0, bf[0], a); a = mfma16(w1v, bf[1], a); }
          if ((m&1)==0){
            a = mfma16(lA[0], bf[2], a); a = mfma16(lA[1], bf[3], a);
            a = mfma16(lA[2], bf[4], a); a = mfma16(lA[3], bf[5], a);
            if (m+2 < 12) LOADA(m+2);
          } else {
            a = mfma16(lB[0], bf[2], a); a = mfma16(lB[1], bf[3], a);
            a = mfma16(lB[2], bf[4], a); a = mfma16(lB[3], bf[5], a);
            if (m+2 < 12) LOADB(m+2);
          }
          *ap = a;
        }
        CELLS(1, ut, wcsr1, a0, a1, a2, a3);
      }
      part += __shfl_xor(part, 16); part += __shfl_xor(part, 32);
      if (l4 == 0) red[1][wid][l15] = part;
      __syncthreads();
      if (tid < 16)
        outs[(sp*2+1)*Bb + b0 + tid] = sigm(red[1][0][tid]+red[1][1][tid]+red[1][2][tid]+red[1][3][tid] + bc1);
    }
  }
#undef LOADA
#undef LOADB
#undef XWINIT
#undef CELLS
}

// ---------------- final softmax over 64 steps ----------------
__global__ __launch_bounds__(256) void fin_k(const float* __restrict__ outs, float* __restrict__ dout)
{
  int row = blockIdx.x*256 + threadIdx.x;
  float v[64]; float mx = -3.0e38f;
  #pragma unroll
  for (int s = 0; s < 64; ++s){ v[s] = outs[s*Bb + row]; mx = fmaxf(mx, v[s]); }
  float sum = 0.0f;
  #pragma unroll
  for (int s = 0; s < 64; ++s){ v[s] = __expf(v[s] - mx); sum += v[s]; }
  float inv = __builtin_amdgcn_rcpf(sum);
  float* p0 = dout + (size_t)Bb*Tt*Ff;
  float* p1 = p0 + Bb*32;
  #pragma unroll
  for (int j = 0; j < 32; ++j) p0[row*32 + j] = v[j]*inv;
  #pragma unroll
  for (int j = 0; j < 32; ++j) p1[row*32 + j] = v[32 + j]*inv;
}

extern "C" void kernel_launch(void* const* d_in, const int* in_sizes, int n_in,
                              void* d_out, int out_size, void* d_ws, size_t ws_size,
                              hipStream_t stream)
{
  const float* x      = (const float*)d_in[0];
  const float* Wih    = (const float*)d_in[1];
  const float* Whh    = (const float*)d_in[2];
  const float* Wlong  = (const float*)d_in[3];
  const float* blong  = (const float*)d_in[4];
  const float* Watt   = (const float*)d_in[5];
  const float* batt   = (const float*)d_in[6];
  const float* Wihcs  = (const float*)d_in[7];
  const float* Whhcs  = (const float*)d_in[8];
  const float* Wcs    = (const float*)d_in[9];
  const float* bcs    = (const float*)d_in[10];
  float* out = (float*)d_out;
  char* ws = (char*)d_ws;

  float* xlast   = (float*)ws;                   // 131072
  float* c0      = (float*)(ws + 131072);        // 2048
  int*   lastobs = (int*)  (ws + 133120);        // 2048
  float* ha      = (float*)(ws + 135168);        // 393216 -> 528384
  u16*   Wd      = (u16*)  (ws + 528384);        // 589824 -> 1118208
  u16*   WdIH    = (u16*)  (ws + 1118208);       // 589824 -> 1708032
  u16*   xwg     = (u16*)  (ws + 1708032);       // 1572864 -> 3280896
  float* outs    = (float*)(ws + 3280896);       // 131072 -> 3411968

  prep_wd_k<<<1152, 256, 0, stream>>>(Whhcs, Wihcs, Wd, WdIH);
  prelim_k<<<Bb, 64, 0, stream>>>(x, Watt, batt, xlast, c0, lastobs);
  enc_k<<<32, 512, 0, stream>>>(x, Whh, Wih, Wlong, blong, Watt, xlast, c0, lastobs, out, ha);
  xw_k<<<384, 64, 0, stream>>>(WdIH, ha, xwg);
  dec_k<<<32, 256, 0, stream>>>(ha, Wd, xwg, Wcs, bcs, outs);
  fin_k<<<2, 256, 0, stream>>>(outs, out);
}

// Round 4
// 583.759 us; speedup vs baseline: 1.0607x; 1.0607x over previous
//
#include <hip/hip_runtime.h>
#include <stdint.h>

#define DEV __device__ __forceinline__
typedef unsigned short u16; typedef unsigned int u32; typedef unsigned long long u64;
typedef __attribute__((ext_vector_type(8))) short s8v;   // 8 x bf16 (4 VGPR)
typedef __attribute__((ext_vector_type(4))) float f4v;   // MFMA acc

#define Bb 512
#define Tt 256
#define Ff 64
#define Hh 128
#define Dd 192

DEV u16 f2bf(float f){ u32 u = __builtin_bit_cast(u32, f); u32 r = (u + 0x7fffu + ((u>>16)&1u)) >> 16; return (u16)r; }
DEV float bf2f(u16 h){ u32 u = ((u32)h)<<16; return __builtin_bit_cast(float, u); }
DEV float sigm(float x){ return __builtin_amdgcn_rcpf(1.0f + __expf(-x)); }
DEV float tanhfast(float x){ return 1.0f - 2.0f*__builtin_amdgcn_rcpf(1.0f + __expf(2.0f*x)); }

DEV f4v mfma16(s8v a, s8v b, f4v c){ return __builtin_amdgcn_mfma_f32_16x16x32_bf16(a, b, c, 0, 0, 0); }

// barrier that orders LDS only — does NOT drain vmcnt (global loads/stores stay in flight)
DEV void barrier_lds(){ asm volatile("s_waitcnt lgkmcnt(0)\n\ts_barrier" ::: "memory"); }

// hx LDS element index for (k, col). Layout: [k/8 block][16 cols (xor-swizzled)][8 k]
DEV int hxe(int k, int c){ int blk = k>>3; return (blk*16 + (c ^ ((blk&3)<<1)))*8 + (k&7); }

DEV s8v pack8(const float* p){
  const float4 a = *(const float4*)p; const float4 b = *(const float4*)(p+4);
  s8v r; r[0]=(short)f2bf(a.x); r[1]=(short)f2bf(a.y); r[2]=(short)f2bf(a.z); r[3]=(short)f2bf(a.w);
  r[4]=(short)f2bf(b.x); r[5]=(short)f2bf(b.y); r[6]=(short)f2bf(b.z); r[7]=(short)f2bf(b.w); return r;
}
DEV u32 pk2(float a, float b){ return (u32)f2bf(a) | ((u32)f2bf(b)<<16); }

// ---------------- prelim: last_obs, x_last, score const term ----------------
__global__ __launch_bounds__(64) void prelim_k(const float* __restrict__ x,
    const float* __restrict__ Watt, const float* __restrict__ batt,
    float* __restrict__ xlast, float* __restrict__ c0, int* __restrict__ lastobs)
{
  int b = blockIdx.x, tid = threadIdx.x;
  int cnt = 0;
  for (int it = 0; it < 4; ++it){
    int t = it*64 + tid;
    const float4* p = (const float4*)(x + ((size_t)b*Tt + t)*Ff);
    float s = 0.0f;
    #pragma unroll
    for (int q = 0; q < 16; ++q){ float4 v = p[q]; s += fabsf(v.x)+fabsf(v.y)+fabsf(v.z)+fabsf(v.w); }
    u64 m = __ballot(s != 0.0f);
    cnt += __popcll(m);
  }
  int last = cnt - 1;
  int li = (last < 0) ? (Tt-1) : last;
  float xl = x[((size_t)b*Tt + li)*Ff + tid];
  xlast[b*Ff + tid] = xl;
  float p = xl * Watt[Hh + tid];
  for (int off = 32; off; off >>= 1) p += __shfl_down(p, off);
  if (tid == 0){ c0[b] = p + batt[0]; lastobs[b] = last; }
}

// ---------------- decoder weight prep: frag-major bf16 for both W_hh_cs and W_ih_cs --------
__global__ __launch_bounds__(256) void prep_wd_k(const float* __restrict__ Whhcs,
    const float* __restrict__ Wihcs, u16* __restrict__ Wd, u16* __restrict__ WdIH)
{
  int idx = blockIdx.x*256 + threadIdx.x;          // < 294912
  int j = idx & 7, lane = (idx>>3)&63;
  int f = idx>>9;                                  // < 576
  int kt = f % 6; int mtr = f/6;                   // mtr < 96
  int mt = mtr % 48, r = mtr/48;
  int ut = mt>>2, g = mt&3;
  int row = g*Dd + ut*16 + (lane&15);
  int k = kt*32 + (lane>>4)*8 + j;
  size_t src = ((size_t)r*768 + row)*Dd + k;
  Wd[idx]   = f2bf(Whhcs[src]);
  WdIH[idx] = f2bf(Wihcs[src]);
}

// ---------------- xw = ha @ W_ih_cs^T  (acc-init fragments, bf16) ----------------
__global__ __launch_bounds__(64) void xw_k(const u16* __restrict__ WdIH,
    const float* __restrict__ ha, u16* __restrict__ xwg)
{
  int lane = threadIdx.x, l15 = lane&15, l4 = lane>>4;
  int cg = blockIdx.x & 3, rm = blockIdx.x >> 2;   // rm < 96
  s8v af[6];
  #pragma unroll
  for (int kt=0;kt<6;++kt) af[kt] = *(const s8v*)(WdIH + (size_t)(rm*6+kt)*512 + lane*8);
  #pragma unroll
  for (int ct=0; ct<8; ++ct){
    int c = cg*128 + ct*16 + l15;
    f4v a = {0,0,0,0};
    #pragma unroll
    for (int kt=0;kt<6;++kt){
      s8v b = pack8(ha + (size_t)c*Dd + kt*32 + l4*8);
      a = mfma16(af[kt], b, a);
    }
    int bg = cg*8 + ct;
    int base = bg*24576 + rm*256 + l15*16 + l4*4;  // elements
    *(u32*)&xwg[base]   = pk2(a[0], a[1]);
    *(u32*)&xwg[base+2] = pk2(a[2], a[3]);
  }
}

// ---------------- encoder: LSTM + fused long_pred + fused online attention ----------------
__global__ __launch_bounds__(512,2) void enc_k(
    const float* __restrict__ x, const float* __restrict__ Whh, const float* __restrict__ Wih,
    const float* __restrict__ Wlong, const float* __restrict__ blong, const float* __restrict__ Watt,
    const float* __restrict__ xlast, const float* __restrict__ c0v, const int* __restrict__ lastobs,
    float* __restrict__ lp_out, float* __restrict__ ha)
{
  __shared__ __align__(16) u16 hx[2][3072];
  __shared__ float lp_lds[2][16*68];
  __shared__ float sarr[2][16];
  const int tid = threadIdx.x, wid = tid>>6, lane = tid&63, l15 = lane&15, l4 = lane>>4;
  const int b0 = blockIdx.x*16;
  const int xrow = tid>>5, xc2 = (tid&31)*2;

  // weight fragments
  s8v wf[4][6];
  #pragma unroll
  for (int mt = 0; mt < 4; ++mt){
    int gate = mt*Hh + wid*16 + l15;
    #pragma unroll
    for (int kt = 0; kt < 6; ++kt){
      int k0 = kt*32 + l4*8;
      if (kt < 4) wf[mt][kt] = pack8(Whh + (size_t)gate*Hh + k0);
      else        wf[mt][kt] = pack8(Wih + (size_t)gate*Ff + (k0 - Hh));
    }
  }
  s8v wfx[6];
  {
    s8v z = {0,0,0,0,0,0,0,0};
    #pragma unroll
    for (int kt = 0; kt < 6; ++kt) wfx[kt] = z;
    if (wid < 4){
      int f = wid*16 + l15;
      #pragma unroll
      for (int kt = 0; kt < 4; ++kt) wfx[kt] = pack8(Wlong + (size_t)f*Hh + kt*32 + l4*8);
    } else if (wid == 4 && l15 == 0){
      #pragma unroll
      for (int kt = 0; kt < 4; ++kt) wfx[kt] = pack8(Watt + kt*32 + l4*8);
    }
  }
  float bl[4] = {0,0,0,0};
  if (wid < 4){
    #pragma unroll
    for (int j = 0; j < 4; ++j) bl[j] = blong[wid*16 + l4*4 + j];
  }
  const int   lastb = lastobs[b0 + l15];
  const float c0b   = c0v[b0 + l15];

  // invariant LDS addresses
  const int he0 = hxe(wid*16 + l4*4, l15);           // h write (b64)
  const int xe0 = hxe(Hh + xc2, xrow);               // x write (b32)

  // init hx[0]: h=0 (k<128 -> first 512 u64), x_0
  ((u64*)hx[0])[tid] = 0ull;
  {
    float2 xv = *(const float2*)(x + ((size_t)(b0+xrow)*Tt + 0)*Ff + xc2);
    *(u32*)&hx[0][xe0] = pk2(xv.x, xv.y);
  }
  // x prefetch: xa holds x_{tb+1..tb+4}
  float2 xa[4], xb[4];
  #pragma unroll
  for (int u = 0; u < 4; ++u)
    xa[u] = *(const float2*)(x + ((size_t)(b0+xrow)*Tt + (1+u))*Ff + xc2);
  __syncthreads();

  float cst[4] = {0,0,0,0}, hp[4] = {0,0,0,0}, hpp[4] = {0,0,0,0};
  float accA[4] = {0,0,0,0}, mrun = -3.0e38f, zrun = 0.0f;

  for (int tb = 0; tb < Tt; tb += 4){
    // prefetch x_{tb+5..tb+8}
    #pragma unroll
    for (int u = 0; u < 4; ++u){
      int tp = tb + 5 + u; if (tp > Tt-1) tp = Tt-1;
      xb[u] = *(const float2*)(x + ((size_t)(b0+xrow)*Tt + tp)*Ff + xc2);
    }
    #pragma unroll
    for (int u = 0; u < 4; ++u){
      const int t = tb + u;
      const int curb = u & 1, nxtb = curb ^ 1;
      s8v bf[6];
      #pragma unroll
      for (int kt = 0; kt < 6; ++kt)
        bf[kt] = *(const s8v*)&hx[curb][((kt*4 + l4)*16 + (l15 ^ (l4<<1)))*8];

      f4v acc0 = {0,0,0,0}, acc1 = {0,0,0,0}, acc2 = {0,0,0,0}, acc3 = {0,0,0,0}, accx = {0,0,0,0};
      #pragma unroll
      for (int kt = 0; kt < 6; ++kt){
        acc0 = mfma16(wf[0][kt], bf[kt], acc0);
        acc1 = mfma16(wf[1][kt], bf[kt], acc1);
        acc2 = mfma16(wf[2][kt], bf[kt], acc2);
        acc3 = mfma16(wf[3][kt], bf[kt], acc3);
      }
      if (wid < 5){
        #pragma unroll
        for (int kt = 0; kt < 6; ++kt) accx = mfma16(wfx[kt], bf[kt], accx);
      }
      if (wid == 4 && l4 == 0) sarr[nxtb][l15] = accx[0] + c0b;   // s_{t-1}

      float hnew[4];
      #pragma unroll
      for (int j = 0; j < 4; ++j){
        float cn = sigm(acc1[j])*cst[j] + sigm(acc0[j])*tanhfast(acc2[j]);
        cst[j] = cn;
        hnew[j] = sigm(acc3[j])*tanhfast(cn);
      }
      // online attention: pair (s_{t-2}, h_{t-2})
      if (t >= 2){
        float sv = sarr[curb][l15];
        if (t-2 < lastb){
          float mn = fmaxf(mrun, sv);
          float sc = __expf(mrun - mn);
          float e  = __expf(sv - mn);
          zrun = zrun*sc + e;
          #pragma unroll
          for (int j = 0; j < 4; ++j) accA[j] = accA[j]*sc + e*hpp[j];
          mrun = mn;
        }
      }
      #pragma unroll
      for (int j = 0; j < 4; ++j){ hpp[j] = hp[j]; hp[j] = hnew[j]; }
      // packed h write
      {
        u64 w = (u64)pk2(hnew[0],hnew[1]) | ((u64)pk2(hnew[2],hnew[3])<<32);
        *(u64*)&hx[nxtb][he0] = w;
      }
      if (t < Tt-1) *(u32*)&hx[nxtb][xe0] = pk2(xa[u].x, xa[u].y);
      if (wid < 4){
        #pragma unroll
        for (int j = 0; j < 4; ++j)
          lp_lds[nxtb][l15*68 + wid*16 + l4*4 + j] = accx[j] + bl[j];   // lp_{t-1}
      }
      if (t >= 2){
        float2 v; v.x = lp_lds[curb][xrow*68 + xc2]; v.y = lp_lds[curb][xrow*68 + xc2 + 1];
        *(float2*)(lp_out + ((size_t)(b0+xrow)*Tt + (t-2))*Ff + xc2) = v;
      }
      barrier_lds();                                   // LDS-only barrier: no vmcnt drain
    }
    #pragma unroll
    for (int u = 0; u < 4; ++u) xa[u] = xb[u];
  }
  // epilogue (after loop: hx[0]=h_255, sarr[0]=s_254, lp_lds[0]=lp_254)
  {
    if (254 < lastb){
      float sv = sarr[0][l15];
      float mn = fmaxf(mrun, sv);
      float sc = __expf(mrun - mn);
      float e  = __expf(sv - mn);
      zrun = zrun*sc + e;
      #pragma unroll
      for (int j = 0; j < 4; ++j) accA[j] = accA[j]*sc + e*hpp[j];
      mrun = mn;
    }
    { float2 v; v.x = lp_lds[0][xrow*68 + xc2]; v.y = lp_lds[0][xrow*68 + xc2 + 1];
      *(float2*)(lp_out + ((size_t)(b0+xrow)*Tt + 254)*Ff + xc2) = v; }
    // lp_255 from h_255
    s8v bfE[4];
    #pragma unroll
    for (int kt = 0; kt < 4; ++kt)
      bfE[kt] = *(const s8v*)&hx[0][((kt*4 + l4)*16 + (l15 ^ (l4<<1)))*8];
    if (wid < 4){
      f4v accx = {0,0,0,0};
      #pragma unroll
      for (int kt = 0; kt < 4; ++kt) accx = mfma16(wfx[kt], bfE[kt], accx);
      #pragma unroll
      for (int j = 0; j < 4; ++j) lp_lds[1][l15*68 + wid*16 + l4*4 + j] = accx[j] + bl[j];
    }
    float inv = (zrun > 0.0f) ? __builtin_amdgcn_rcpf(zrun) : 0.0f;
    #pragma unroll
    for (int j = 0; j < 4; ++j)
      ha[(size_t)(b0 + l15)*Dd + wid*16 + l4*4 + j] = accA[j]*inv;
    __syncthreads();
    { float2 v; v.x = lp_lds[1][xrow*68 + xc2]; v.y = lp_lds[1][xrow*68 + xc2 + 1];
      *(float2*)(lp_out + ((size_t)(b0+xrow)*Tt + 255)*Ff + xc2) = v; }
    for (int q = tid; q < 16*Ff; q += 512){
      int r2 = q >> 6, f = q & 63;
      ha[(size_t)(b0 + r2)*Dd + Hh + f] = xlast[(b0 + r2)*Ff + f];
    }
  }
}

// ---------------- decoder v3: risk0 in regs, risk1 LDS(kt0,1) + 3-slot streamed(kt2..5) ------
__global__ __launch_bounds__(256,1) void dec_k(const float* __restrict__ ha,
    const u16* __restrict__ Wd, const u16* __restrict__ xwg,
    const float* __restrict__ Wcs, const float* __restrict__ bcs, float* __restrict__ outs)
{
  __shared__ __align__(16) u16 hx[2][3072];          // 12 KB
  __shared__ __align__(16) u16 w1[48*2*512];         // 96 KB: risk1 kt0,1 frag chunks
  __shared__ __align__(16) u16 xwl[2*48*256];        // 48 KB: acc-init frags
  __shared__ float red[2][4][16];
  const int tid = threadIdx.x, wid = tid>>6, lane = tid&63, l15 = lane&15, l4 = lane>>4;
  const int b0 = blockIdx.x*16;

  // ha -> hx[0]
  #pragma unroll
  for (int it = 0; it < 3; ++it){
    int k = it*64 + (tid>>4)*4, c = tid&15;
    float4 v = *(const float4*)(ha + (size_t)(b0+c)*Dd + k);
    int e = hxe(k, c);
    *(u32*)&hx[0][e]   = pk2(v.x, v.y);
    *(u32*)&hx[0][e+2] = pk2(v.z, v.w);
  }
  // xwl copy (49152 B)
  {
    const u16* src = xwg + (size_t)blockIdx.x*24576;
    #pragma unroll
    for (int i = 0; i < 12; ++i){
      int off = (i*256 + tid)*8;
      *(s8v*)&xwl[off] = *(const s8v*)(src + off);
    }
  }
  // w1 copy: dst chunk (mtg*2+kt)*512  <-  Wd[((48+mtg)*6+kt)*512]
  #pragma unroll
  for (int i = 0; i < 24; ++i){
    int off = (i*256 + tid)*8;
    int chunk = off>>9, inner = off&511;
    int mtg = chunk>>1, kt = chunk&1;
    *(s8v*)&w1[off] = *(const s8v*)(Wd + (size_t)((48+mtg)*6+kt)*512 + inner);
  }
  // risk0 weights in registers
  s8v wreg[12][6];
  #pragma unroll
  for (int m = 0; m < 12; ++m)
    #pragma unroll
    for (int kt = 0; kt < 6; ++kt)
      wreg[m][kt] = *(const s8v*)(Wd + (size_t)((wid*12+m)*6+kt)*512 + lane*8);

  float cst[3][4], wcsr0[3][4], wcsr1[3][4];
  #pragma unroll
  for (int ut = 0; ut < 3; ++ut){
    int u0 = (wid*3+ut)*16 + l4*4;
    #pragma unroll
    for (int jj = 0; jj < 4; ++jj){
      cst[ut][jj]   = ha[(size_t)(b0+l15)*Dd + u0 + jj];
      wcsr0[ut][jj] = Wcs[u0 + jj];
      wcsr1[ut][jj] = Wcs[Dd + u0 + jj];
    }
  }
  const float bc0 = bcs[0], bc1 = bcs[1];
  __syncthreads();

  const u16* wsb = Wd + (size_t)(48 + wid*12)*6*512 + lane*8;   // risk1 stream base
  s8v st[3][4];                                                 // 3-slot rotation (48 VGPR)
#define LOADS(sl_, m_) { _Pragma("unroll") for (int q=0;q<4;++q) st[sl_][q] = *(const s8v*)(wsb + (size_t)((m_)*6 + 2 + q)*512); }

#define XWINIT(r_, m_, a_) { \
    int xb_ = ((r_)*48 + wid*12 + (m_))*256 + l15*16 + l4*4; \
    u32 q0 = *(const u32*)&xwl[xb_]; u32 q1 = *(const u32*)&xwl[xb_+2]; \
    a_[0] = bf2f((u16)q0); a_[1] = bf2f((u16)(q0>>16)); \
    a_[2] = bf2f((u16)q1); a_[3] = bf2f((u16)(q1>>16)); }

#define CELLS(r_, ut_, wcs_, a0_, a1_, a2_, a3_) { \
    float hn0,hn1,hn2,hn3; \
    { float cn = sigm(a1_[0])*cst[ut_][0] + sigm(a0_[0])*tanhfast(a2_[0]); cst[ut_][0]=cn; hn0 = sigm(a3_[0])*tanhfast(cn); } \
    { float cn = sigm(a1_[1])*cst[ut_][1] + sigm(a0_[1])*tanhfast(a2_[1]); cst[ut_][1]=cn; hn1 = sigm(a3_[1])*tanhfast(cn); } \
    { float cn = sigm(a1_[2])*cst[ut_][2] + sigm(a0_[2])*tanhfast(a2_[2]); cst[ut_][2]=cn; hn2 = sigm(a3_[2])*tanhfast(cn); } \
    { float cn = sigm(a1_[3])*cst[ut_][3] + sigm(a0_[3])*tanhfast(a2_[3]); cst[ut_][3]=cn; hn3 = sigm(a3_[3])*tanhfast(cn); } \
    part += hn0*wcs_[ut_][0] + hn1*wcs_[ut_][1] + hn2*wcs_[ut_][2] + hn3*wcs_[ut_][3]; \
    int u0_ = (wid*3+(ut_))*16 + l4*4; \
    int e0_ = (((u0_>>3)*16) + (l15 ^ (((u0_>>3)&3)<<1)))*8 + (u0_&7); \
    u64 w_ = (u64)pk2(hn0,hn1) | ((u64)pk2(hn2,hn3)<<32); \
    *(u64*)&hx[nxtb_][e0_] = w_; }

  for (int sp = 0; sp < 32; ++sp){
    // ---------- EVEN step s=2sp, r=0: reads hx[0], writes hx[1] ----------
    {
      LOADS(0, 0); LOADS(1, 1); LOADS(2, 2);      // prefetch odd-step streams m=0..2
      const int nxtb_ = 1;
      s8v bf[6];
      #pragma unroll
      for (int kt = 0; kt < 6; ++kt)
        bf[kt] = *(const s8v*)&hx[0][((kt*4 + l4)*16 + (l15 ^ (l4<<1)))*8];
      float part = 0.0f;
      #pragma unroll
      for (int ut = 0; ut < 3; ++ut){
        f4v a0,a1,a2,a3;
        XWINIT(0, ut*4+0, a0); XWINIT(0, ut*4+1, a1); XWINIT(0, ut*4+2, a2); XWINIT(0, ut*4+3, a3);
        #pragma unroll
        for (int kt = 0; kt < 6; ++kt){
          a0 = mfma16(wreg[ut*4+0][kt], bf[kt], a0);
          a1 = mfma16(wreg[ut*4+1][kt], bf[kt], a1);
          a2 = mfma16(wreg[ut*4+2][kt], bf[kt], a2);
          a3 = mfma16(wreg[ut*4+3][kt], bf[kt], a3);
        }
        CELLS(0, ut, wcsr0, a0, a1, a2, a3);
      }
      part += __shfl_xor(part, 16); part += __shfl_xor(part, 32);
      if (l4 == 0) red[0][wid][l15] = part;
      barrier_lds();
      if (tid < 16)
        outs[(sp*2)*Bb + b0 + tid] = sigm(red[0][0][tid]+red[0][1][tid]+red[0][2][tid]+red[0][3][tid] + bc0);
    }
    // ---------- ODD step s=2sp+1, r=1: reads hx[1], writes hx[0] ----------
    {
      const int nxtb_ = 0;
      s8v bf[6];
      #pragma unroll
      for (int kt = 0; kt < 6; ++kt)
        bf[kt] = *(const s8v*)&hx[1][((kt*4 + l4)*16 + (l15 ^ (l4<<1)))*8];
      float part = 0.0f;
      #pragma unroll
      for (int ut = 0; ut < 3; ++ut){
        f4v a0,a1,a2,a3;
        XWINIT(1, ut*4+0, a0); XWINIT(1, ut*4+1, a1); XWINIT(1, ut*4+2, a2); XWINIT(1, ut*4+3, a3);
        #pragma unroll
        for (int g = 0; g < 4; ++g){
          const int m = ut*4 + g;
          const int sl = m % 3;
          f4v* ap = (g==0)? &a0 : (g==1)? &a1 : (g==2)? &a2 : &a3;
          f4v a = *ap;
          { s8v w0 = *(const s8v*)&w1[((wid*12+m)*2+0)*512 + lane*8];
            s8v w1v= *(const s8v*)&w1[((wid*12+m)*2+1)*512 + lane*8];
            a = mfma16(w0, bf[0], a); a = mfma16(w1v, bf[1], a); }
          a = mfma16(st[sl][0], bf[2], a); a = mfma16(st[sl][1], bf[3], a);
          a = mfma16(st[sl][2], bf[4], a); a = mfma16(st[sl][3], bf[5], a);
          if (m+3 < 12) LOADS(sl, m+3);
          *ap = a;
        }
        CELLS(1, ut, wcsr1, a0, a1, a2, a3);
      }
      part += __shfl_xor(part, 16); part += __shfl_xor(part, 32);
      if (l4 == 0) red[1][wid][l15] = part;
      barrier_lds();
      if (tid < 16)
        outs[(sp*2+1)*Bb + b0 + tid] = sigm(red[1][0][tid]+red[1][1][tid]+red[1][2][tid]+red[1][3][tid] + bc1);
    }
  }
#undef LOADS
#undef XWINIT
#undef CELLS
}

// ---------------- final softmax over 64 steps ----------------
__global__ __launch_bounds__(256) void fin_k(const float* __restrict__ outs, float* __restrict__ dout)
{
  int row = blockIdx.x*256 + threadIdx.x;
  float v[64]; float mx = -3.0e38f;
  #pragma unroll
  for (int s = 0; s < 64; ++s){ v[s] = outs[s*Bb + row]; mx = fmaxf(mx, v[s]); }
  float sum = 0.0f;
  #pragma unroll
  for (int s = 0; s < 64; ++s){ v[s] = __expf(v[s] - mx); sum += v[s]; }
  float inv = __builtin_amdgcn_rcpf(sum);
  float* p0 = dout + (size_t)Bb*Tt*Ff;
  float* p1 = p0 + Bb*32;
  #pragma unroll
  for (int j = 0; j < 32; ++j) p0[row*32 + j] = v[j]*inv;
  #pragma unroll
  for (int j = 0; j < 32; ++j) p1[row*32 + j] = v[32 + j]*inv;
}

extern "C" void kernel_launch(void* const* d_in, const int* in_sizes, int n_in,
                              void* d_out, int out_size, void* d_ws, size_t ws_size,
                              hipStream_t stream)
{
  const float* x      = (const float*)d_in[0];
  const float* Wih    = (const float*)d_in[1];
  const float* Whh    = (const float*)d_in[2];
  const float* Wlong  = (const float*)d_in[3];
  const float* blong  = (const float*)d_in[4];
  const float* Watt   = (const float*)d_in[5];
  const float* batt   = (const float*)d_in[6];
  const float* Wihcs  = (const float*)d_in[7];
  const float* Whhcs  = (const float*)d_in[8];
  const float* Wcs    = (const float*)d_in[9];
  const float* bcs    = (const float*)d_in[10];
  float* out = (float*)d_out;
  char* ws = (char*)d_ws;

  float* xlast   = (float*)ws;                   // 131072
  float* c0      = (float*)(ws + 131072);        // 2048
  int*   lastobs = (int*)  (ws + 133120);        // 2048
  float* ha      = (float*)(ws + 135168);        // 393216 -> 528384
  u16*   Wd      = (u16*)  (ws + 528384);        // 589824 -> 1118208
  u16*   WdIH    = (u16*)  (ws + 1118208);       // 589824 -> 1708032
  u16*   xwg     = (u16*)  (ws + 1708032);       // 1572864 -> 3280896
  float* outs    = (float*)(ws + 3280896);       // 131072 -> 3411968

  prep_wd_k<<<1152, 256, 0, stream>>>(Whhcs, Wihcs, Wd, WdIH);
  prelim_k<<<Bb, 64, 0, stream>>>(x, Watt, batt, xlast, c0, lastobs);
  enc_k<<<32, 512, 0, stream>>>(x, Whh, Wih, Wlong, blong, Watt, xlast, c0, lastobs, out, ha);
  xw_k<<<384, 64, 0, stream>>>(WdIH, ha, xwg);
  dec_k<<<32, 256, 0, stream>>>(ha, Wd, xwg, Wcs, bcs, outs);
  fin_k<<<2, 256, 0, stream>>>(outs, out);
}